// Round 5
// baseline (172.908 us; speedup 1.0000x reference)
//
#include <hip/hip_runtime.h>
#include <hip/hip_fp16.h>

#define N_NODES 100000
#define CCH 64
#define E_EDGES 1600000
#define HH 8
#define ETHR 1024            // main edge kernel: 16 waves/block
#define TAIL_E 100000        // edges whose out-slots host the node table (3.2 MB / 32 B)
#define EMAIN (E_EDGES - TAIL_E)   // 1,500,000

typedef float v4f __attribute__((ext_vector_type(4)));

// Node table: node n -> 32 B = [srcRec 16 B | dstRec 16 B], fp16 p[4]+q (+pad).
// NO d_ws: table lives in the last 3.2 MB of d_out (outputs of edges [EMAIN,E)).
// Experiment: the 256 MiB ws poison fills (41 us each, 2/iter) dominate the
// 113 us fixed overhead. If they are conditional on ws use, this saves ~80 us.
// Schedule (one stream, race-free): node_pre writes table -> edge_k (edges
// [0,EMAIN), reads table, writes disjoint out) -> edge_tail (edges [EMAIN,E),
// computes directly from x in f32, overwrites the table region, reads no table).
union RecU {
    uint4  v;
    __half h[8];
};

__global__ __launch_bounds__(256) void node_pre(
    const float* __restrict__ x,
    const int* __restrict__ layer_idx_p,
    const float* __restrict__ psi_w,
    const float* __restrict__ psi_b,
    const float* __restrict__ delta_w,
    const float* __restrict__ u,
    uint4* __restrict__ recs)          // recs[2n] = src, recs[2n+1] = dst
{
    __shared__ float4 s_w0[CCH];
    __shared__ float4 s_w1[CCH];
    __shared__ float  s_b0[CCH];
    __shared__ float  s_b1[CCH];

    int li = layer_idx_p[0];
    for (int i = threadIdx.x; i < 2 * CCH; i += blockDim.x) {
        float4 w = make_float4(psi_w[i * 4 + 0], psi_w[i * 4 + 1],
                               psi_w[i * 4 + 2], psi_w[i * 4 + 3]);
        float bb = psi_b[i] + delta_w[li * 2 * CCH + i] + u[li * 2 * CCH + i];
        if (i < CCH) { s_w0[i] = w; s_b0[i] = bb; }
        else         { s_w1[i - CCH] = w; s_b1[i - CCH] = bb; }
    }
    __syncthreads();

    int n = blockIdx.x * blockDim.x + threadIdx.x;
    if (n >= N_NODES) return;

    const float4* xr = (const float4*)(x + (size_t)n * CCH);
    float a0 = 0, a1 = 0, a2 = 0, a3 = 0, aq = 0;
    float c0 = 0, c1 = 0, c2 = 0, c3 = 0, cq = 0;
#pragma unroll
    for (int it = 0; it < CCH / 4; ++it) {
        float4 xv4 = xr[it];
        float xv[4] = { xv4.x, xv4.y, xv4.z, xv4.w };
#pragma unroll
        for (int j = 0; j < 4; ++j) {
            int c = it * 4 + j;
            float xv_ = xv[j];
            float4 w0 = s_w0[c];
            float4 w1 = s_w1[c];
            a0 += xv_ * w0.x; a1 += xv_ * w0.y; a2 += xv_ * w0.z; a3 += xv_ * w0.w;
            aq += xv_ * s_b0[c];
            c0 += xv_ * w1.x; c1 += xv_ * w1.y; c2 += xv_ * w1.z; c3 += xv_ * w1.w;
            cq += xv_ * s_b1[c];
        }
    }
    RecU rs;
    rs.h[0] = __float2half_rn(a0); rs.h[1] = __float2half_rn(a1);
    rs.h[2] = __float2half_rn(a2); rs.h[3] = __float2half_rn(a3);
    rs.h[4] = __float2half_rn(aq);
    rs.h[5] = __half(0.0f); rs.h[6] = __half(0.0f); rs.h[7] = __half(0.0f);
    RecU rd;
    rd.h[0] = __float2half_rn(c0); rd.h[1] = __float2half_rn(c1);
    rd.h[2] = __float2half_rn(c2); rd.h[3] = __float2half_rn(c3);
    rd.h[4] = __float2half_rn(cq);
    rd.h[5] = __half(0.0f); rd.h[6] = __half(0.0f); rd.h[7] = __half(0.0f);
    recs[2 * (size_t)n]     = rs.v;
    recs[2 * (size_t)n + 1] = rd.v;
}

// Main edge kernel: edges [0, EMAIN). Round-4 structure (session-best ~30 us
// over full E): dense loads, 2 gathers/edge (minimum), LDS base-stage so every
// store instruction is 64x16 B contiguous (full lines only).
__global__ __launch_bounds__(ETHR) void edge_k(
    const int* __restrict__ ei,
    const float* __restrict__ sf,
    const int* __restrict__ layer_idx_p,
    const float* __restrict__ gamma_h,
    const uint4* __restrict__ recs,
    float* __restrict__ out)
{
    __shared__ float s_g[HH];
    __shared__ float s_b[ETHR];

    if (threadIdx.x < HH) {
        int li = layer_idx_p[0];
        s_g[threadIdx.x] = gamma_h[li * HH + threadIdx.x];
    }

    int e  = blockIdx.x * ETHR + threadIdx.x;
    int ee = (e < EMAIN) ? e : (EMAIN - 1);   // clamp: safe redundant work in tail

    int row = __builtin_nontemporal_load(ei + ee);              // 4 B/lane dense
    int col = __builtin_nontemporal_load(ei + E_EDGES + ee);    // 4 B/lane dense
    v4f f   = __builtin_nontemporal_load((const v4f*)sf + ee);  // 16 B/lane dense

    RecU rs; rs.v = recs[2 * (size_t)row];       // src record of row (16 B gather)
    RecU rd; rd.v = recs[2 * (size_t)col + 1];   // dst record of col (16 B gather)

    float s = f.x * (__half2float(rs.h[0]) + __half2float(rd.h[0]))
            + f.y * (__half2float(rs.h[1]) + __half2float(rd.h[1]))
            + f.z * (__half2float(rs.h[2]) + __half2float(rd.h[2]))
            + f.w * (__half2float(rs.h[3]) + __half2float(rd.h[3]))
            + __half2float(rs.h[4]) + __half2float(rd.h[4]);
    float base = (s > 0.0f) ? s : 0.01f * s;

    s_b[threadIdx.x] = base;
    __syncthreads();   // single barrier: covers s_g and s_b

    // Store phase: block owns 2*ETHR v4f slabs; local v4f index l -> edge l>>1,
    // gamma-half l&1. Thread t writes l=t and l=ETHR+t (same half t&1).
    int t = threadIdx.x;
    float b0v = s_b[t >> 1];                  // 2-way same-address broadcast: conflict-free
    float b1v = s_b[(t >> 1) + (ETHR / 2)];
    const int go = (t & 1) * 4;
    float g0 = s_g[go + 0], g1 = s_g[go + 1], g2 = s_g[go + 2], g3 = s_g[go + 3];
    v4f o0 = { g0 * b0v, g1 * b0v, g2 * b0v, g3 * b0v };
    v4f o1 = { g0 * b1v, g1 * b1v, g2 * b1v, g3 * b1v };

    size_t vbase = (size_t)blockIdx.x * (2 * ETHR);
    v4f* op = (v4f*)out;
    int e0 = blockIdx.x * ETHR + (t >> 1);    // edge of first write
    if (e0 < EMAIN)
        __builtin_nontemporal_store(o0, op + vbase + t);
    if (e0 + ETHR / 2 < EMAIN)
        __builtin_nontemporal_store(o1, op + vbase + ETHR + t);
}

// Tail: edges [EMAIN, E). One wave per edge, computed directly from x (f32,
// no table). Lane c holds psi rows c and 64+c in registers; x-row reads are
// 64x4 B coalesced. Overwrites the table region AFTER edge_k (stream order).
__global__ __launch_bounds__(256) void edge_tail(
    const float* __restrict__ x,
    const int* __restrict__ ei,
    const float* __restrict__ sf,
    const int* __restrict__ layer_idx_p,
    const float* __restrict__ psi_w,
    const float* __restrict__ psi_b,
    const float* __restrict__ delta_w,
    const float* __restrict__ u,
    const float* __restrict__ gamma_h,
    float* __restrict__ out)
{
    int li   = layer_idx_p[0];
    int lane = threadIdx.x & 63;
    int wv   = (blockIdx.x * blockDim.x + threadIdx.x) >> 6;   // global wave id
    if (wv >= TAIL_E) return;
    int e = EMAIN + wv;

    // Per-lane psi coefficients (dense float4 loads, lane-indexed -> coalesced).
    float4 w0 = *(const float4*)(psi_w + (size_t)lane * 4);            // src row c
    float4 w1 = *(const float4*)(psi_w + (size_t)(CCH + lane) * 4);    // dst row 64+c
    int ofs = li * 2 * CCH;
    float b0 = psi_b[lane]       + delta_w[ofs + lane]       + u[ofs + lane];
    float b1 = psi_b[CCH + lane] + delta_w[ofs + CCH + lane] + u[ofs + CCH + lane];

    int row = ei[e];
    int col = ei[E_EDGES + e];
    float4 f4 = *(const float4*)(sf + (size_t)e * 4);   // lane-uniform -> broadcast

    float c0 = w0.x * f4.x + w0.y * f4.y + w0.z * f4.z + w0.w * f4.w + b0;
    float c1 = w1.x * f4.x + w1.y * f4.y + w1.z * f4.z + w1.w * f4.w + b1;

    float xs = x[(size_t)row * CCH + lane];   // 256 B coalesced row read
    float xd = x[(size_t)col * CCH + lane];
    float part = xs * c0 + xd * c1;

#pragma unroll
    for (int off = 32; off > 0; off >>= 1)
        part += __shfl_down(part, off);
    float s = __shfl(part, 0);
    float base = (s > 0.0f) ? s : 0.01f * s;

    if (lane < HH)
        out[(size_t)e * HH + lane] = gamma_h[li * HH + lane] * base;
}

extern "C" void kernel_launch(void* const* d_in, const int* in_sizes, int n_in,
                              void* d_out, int out_size, void* d_ws, size_t ws_size,
                              hipStream_t stream) {
    const float* x       = (const float*)d_in[0];
    const int*   ei      = (const int*)d_in[1];
    const float* sf      = (const float*)d_in[2];
    const int*   li      = (const int*)d_in[3];
    const float* psi_w   = (const float*)d_in[4];
    const float* psi_b   = (const float*)d_in[5];
    const float* delta_w = (const float*)d_in[6];
    const float* u       = (const float*)d_in[7];
    const float* gamma_h = (const float*)d_in[8];
    float* out = (float*)d_out;

    // Table lives in the out-slots of the tail edges: out + EMAIN*8 floats
    // = 48,000,000 B offset (16 B aligned). d_ws is deliberately UNUSED.
    uint4* recs = (uint4*)(out + (size_t)EMAIN * HH);

    node_pre<<<(N_NODES + 255) / 256, 256, 0, stream>>>(
        x, li, psi_w, psi_b, delta_w, u, recs);

    edge_k<<<(EMAIN + ETHR - 1) / ETHR, ETHR, 0, stream>>>(
        ei, sf, li, gamma_h, recs, out);

    edge_tail<<<(TAIL_E * 64) / 256, 256, 0, stream>>>(
        x, ei, sf, li, psi_w, psi_b, delta_w, u, gamma_h, out);
}

// Round 6
// 144.789 us; speedup vs baseline: 1.1942x; 1.1942x over previous
//
#include <hip/hip_runtime.h>
#include <hip/hip_fp16.h>

#define N_NODES 100000
#define CCH 64
#define E_EDGES 1600000
#define HH 8
#define ETHR 1024   // 16 waves/block, 2 blocks/CU -> 32 waves/CU

typedef float v4f __attribute__((ext_vector_type(4)));

// Unified interleaved table: node n -> 32 B = [srcRec 16 B | dstRec 16 B].
// Each record: p[4], q as fp16 (+3 pad). Total 3.2 MB -> L2-resident.
// 2 gathers + 2 lines per edge is the minimum (one line per endpoint).
// Ledger: r0 (EPT=1, dense loads, stride-32B stores)   edge_k ~32.3 us
//         r1 (split tables: 4 gathers/edge)            edge_k  54   us  -> scattered gather ~4.5cyc/instr
//         r3 (EPT=2: stride-64B stores)                edge_k  46   us, WRITE 72MB (1.4x ampl.)
//         r4 (this structure: LDS-staged dense stores) edge_k ~30   us  SESSION BEST, total 143.3
//         r5 (no-ws experiment)                        ws poison fills are UNCONDITIONAL (~90us fixed)
union RecU {
    uint4  v;
    __half h[8];
};

__global__ __launch_bounds__(256) void node_pre(
    const float* __restrict__ x,
    const int* __restrict__ layer_idx_p,
    const float* __restrict__ psi_w,
    const float* __restrict__ psi_b,
    const float* __restrict__ delta_w,
    const float* __restrict__ u,
    uint4* __restrict__ recs)          // recs[2n] = src, recs[2n+1] = dst
{
    __shared__ float4 s_w0[CCH];
    __shared__ float4 s_w1[CCH];
    __shared__ float  s_b0[CCH];
    __shared__ float  s_b1[CCH];

    int li = layer_idx_p[0];
    for (int i = threadIdx.x; i < 2 * CCH; i += blockDim.x) {
        float4 w = make_float4(psi_w[i * 4 + 0], psi_w[i * 4 + 1],
                               psi_w[i * 4 + 2], psi_w[i * 4 + 3]);
        float bb = psi_b[i] + delta_w[li * 2 * CCH + i] + u[li * 2 * CCH + i];
        if (i < CCH) { s_w0[i] = w; s_b0[i] = bb; }
        else         { s_w1[i - CCH] = w; s_b1[i - CCH] = bb; }
    }
    __syncthreads();

    int n = blockIdx.x * blockDim.x + threadIdx.x;
    if (n >= N_NODES) return;

    const float4* xr = (const float4*)(x + (size_t)n * CCH);
    float a0 = 0, a1 = 0, a2 = 0, a3 = 0, aq = 0;
    float c0 = 0, c1 = 0, c2 = 0, c3 = 0, cq = 0;
#pragma unroll
    for (int it = 0; it < CCH / 4; ++it) {
        float4 xv4 = xr[it];
        float xv[4] = { xv4.x, xv4.y, xv4.z, xv4.w };
#pragma unroll
        for (int j = 0; j < 4; ++j) {
            int c = it * 4 + j;
            float xv_ = xv[j];
            float4 w0 = s_w0[c];
            float4 w1 = s_w1[c];
            a0 += xv_ * w0.x; a1 += xv_ * w0.y; a2 += xv_ * w0.z; a3 += xv_ * w0.w;
            aq += xv_ * s_b0[c];
            c0 += xv_ * w1.x; c1 += xv_ * w1.y; c2 += xv_ * w1.z; c3 += xv_ * w1.w;
            cq += xv_ * s_b1[c];
        }
    }
    RecU rs;
    rs.h[0] = __float2half_rn(a0); rs.h[1] = __float2half_rn(a1);
    rs.h[2] = __float2half_rn(a2); rs.h[3] = __float2half_rn(a3);
    rs.h[4] = __float2half_rn(aq);
    rs.h[5] = __half(0.0f); rs.h[6] = __half(0.0f); rs.h[7] = __half(0.0f);
    RecU rd;
    rd.h[0] = __float2half_rn(c0); rd.h[1] = __float2half_rn(c1);
    rd.h[2] = __float2half_rn(c2); rd.h[3] = __float2half_rn(c3);
    rd.h[4] = __float2half_rn(cq);
    rd.h[5] = __half(0.0f); rd.h[6] = __half(0.0f); rd.h[7] = __half(0.0f);
    recs[2 * (size_t)n]     = rs.v;
    recs[2 * (size_t)n + 1] = rd.v;
}

// Per-edge kernel: 1 edge/thread, all loads fully dense, 2 gathers/edge
// (minimum), LDS base-stage so every store instruction is 64x16 B contiguous
// (full lines only).
__global__ __launch_bounds__(ETHR) void edge_k(
    const int* __restrict__ ei,
    const float* __restrict__ sf,
    const int* __restrict__ layer_idx_p,
    const float* __restrict__ gamma_h,
    const uint4* __restrict__ recs,
    float* __restrict__ out)
{
    __shared__ float s_g[HH];
    __shared__ float s_b[ETHR];

    if (threadIdx.x < HH) {
        int li = layer_idx_p[0];
        s_g[threadIdx.x] = gamma_h[li * HH + threadIdx.x];
    }

    int e  = blockIdx.x * ETHR + threadIdx.x;
    int ee = (e < E_EDGES) ? e : (E_EDGES - 1);   // clamp: safe redundant work in tail

    int row = __builtin_nontemporal_load(ei + ee);              // 4 B/lane dense
    int col = __builtin_nontemporal_load(ei + E_EDGES + ee);    // 4 B/lane dense
    v4f f   = __builtin_nontemporal_load((const v4f*)sf + ee);  // 16 B/lane dense

    RecU rs; rs.v = recs[2 * (size_t)row];       // src record of row (16 B gather)
    RecU rd; rd.v = recs[2 * (size_t)col + 1];   // dst record of col (16 B gather)

    float s = f.x * (__half2float(rs.h[0]) + __half2float(rd.h[0]))
            + f.y * (__half2float(rs.h[1]) + __half2float(rd.h[1]))
            + f.z * (__half2float(rs.h[2]) + __half2float(rd.h[2]))
            + f.w * (__half2float(rs.h[3]) + __half2float(rd.h[3]))
            + __half2float(rs.h[4]) + __half2float(rd.h[4]);
    float base = (s > 0.0f) ? s : 0.01f * s;

    s_b[threadIdx.x] = base;
    __syncthreads();   // single barrier: covers s_g and s_b

    // Store phase: block owns 2*ETHR v4f slabs; local v4f index l -> edge l>>1,
    // gamma-half l&1. Thread t writes l=t and l=ETHR+t (same half t&1).
    int t = threadIdx.x;
    float b0v = s_b[t >> 1];                  // 2-way same-address broadcast: conflict-free
    float b1v = s_b[(t >> 1) + (ETHR / 2)];
    const int go = (t & 1) * 4;
    float g0 = s_g[go + 0], g1 = s_g[go + 1], g2 = s_g[go + 2], g3 = s_g[go + 3];
    v4f o0 = { g0 * b0v, g1 * b0v, g2 * b0v, g3 * b0v };
    v4f o1 = { g0 * b1v, g1 * b1v, g2 * b1v, g3 * b1v };

    size_t vbase = (size_t)blockIdx.x * (2 * ETHR);
    v4f* op = (v4f*)out;
    int e0 = blockIdx.x * ETHR + (t >> 1);    // edge of first write
    if (e0 < E_EDGES)
        __builtin_nontemporal_store(o0, op + vbase + t);
    if (e0 + ETHR / 2 < E_EDGES)
        __builtin_nontemporal_store(o1, op + vbase + ETHR + t);
}

extern "C" void kernel_launch(void* const* d_in, const int* in_sizes, int n_in,
                              void* d_out, int out_size, void* d_ws, size_t ws_size,
                              hipStream_t stream) {
    const float* x       = (const float*)d_in[0];
    const int*   ei      = (const int*)d_in[1];
    const float* sf      = (const float*)d_in[2];
    const int*   li      = (const int*)d_in[3];
    const float* psi_w   = (const float*)d_in[4];
    const float* psi_b   = (const float*)d_in[5];
    const float* delta_w = (const float*)d_in[6];
    const float* u       = (const float*)d_in[7];
    const float* gamma_h = (const float*)d_in[8];
    float* out = (float*)d_out;

    uint4* recs = (uint4*)d_ws;   // 2 * N * 16 B = 3.2 MB interleaved table

    node_pre<<<(N_NODES + 255) / 256, 256, 0, stream>>>(
        x, li, psi_w, psi_b, delta_w, u, recs);

    edge_k<<<(E_EDGES + ETHR - 1) / ETHR, ETHR, 0, stream>>>(
        ei, sf, li, gamma_h, recs, out);
}